// Round 9
// baseline (111.275 us; speedup 1.0000x reference)
//
#include <hip/hip_runtime.h>
#include <math.h>

#define NS 256
#define EMB 120
#define NBLK 60
#define MODES 16
#define NPH 8

// ws layout (ws >= 4 MB; harness poisons it each iteration with a uniform fill):
//   [0, 256KB)            : Vws (float2[256*16*8])
//   +1MB  + s*64          : done flags, one 64B line per sample s
//   +1MB + 16KB           : never-written reference word (same 64B alignment
//                           class as the flags, so any fill pattern with period
//                           dividing 64B gives flag_init == ref)
#define WS_DONE_OFF (1u << 20)
#define WS_REF_OFF  ((1u << 20) + 256u * 64u)

typedef float v2f __attribute__((ext_vector_type(2)));

// complex mul
__device__ __forceinline__ v2f cmul(v2f a, v2f b) {
    v2f axx = {a.x, a.x};
    v2f nyy = {-a.y, a.y};
    v2f byx = {b.y, b.x};
    return axx * b + nyy * byx;   // {ax*bx - ay*by, ax*by + ay*bx}
}
// r = conj(a)*b + c
__device__ __forceinline__ v2f cfma_conj(v2f a, v2f b, v2f c) {
    v2f axx = {a.x, a.x};
    v2f pyy = {a.y, -a.y};
    v2f byx = {b.y, b.x};
    return axx * b + (pyy * byx + c);
}

// Cross-lane xor within quad via DPP quad_perm (VALU, not LDS pipe).
// xor1: [1,0,3,2] -> ctrl 0xB1 ; xor2: [2,3,0,1] -> ctrl 0x4E
__device__ __forceinline__ float dpp_xor1(float x) {
    return __builtin_bit_cast(float,
        __builtin_amdgcn_mov_dpp(__builtin_bit_cast(int, x), 0xB1, 0xF, 0xF, true));
}
__device__ __forceinline__ float dpp_xor2(float x) {
    return __builtin_bit_cast(float,
        __builtin_amdgcn_mov_dpp(__builtin_bit_cast(int, x), 0x4E, 0xF, 0xF, true));
}

// SINGLE-NODE fused kernel via producer->consumer flag handshake.
// Session algebra (R1/R5/R8): each kernel node costs ~5-8us of launch/ramp
// overhead on top of ~4us compute — node count, not kernel content, is the
// remaining lever. Coop launch failed under graph capture (R7); this uses the
// G16-blessed device-scope-atomic pattern instead. One-directional dependency:
// blocks 0..255 run phase A (R8 emb, verbatim) and publish per-sample flags
// with RELEASE/AGENT stores; all 528 blocks spin on the 16 flags their tile
// pair needs, then stage Vws via AGENT-scope 64-bit atomic loads (bypassing
// possibly-stale per-XCD L2). Deadlock-free: grid 528 <= capacity 1024
// (launch_bounds(256,4), LDS 18.4KB, VGPR<=128), producers never wait.
// Poison-agnostic flags: TOKEN = P ^ const where P is read from a
// never-written ws word each launch.
__global__ __launch_bounds__(256, 4) void fused_flag_kernel(
    const float* __restrict__ x, const float* __restrict__ W,
    const float* __restrict__ bias, float* __restrict__ out_emb,
    float* __restrict__ outK, float2* __restrict__ Vws,
    unsigned char* __restrict__ wsb)
{
    unsigned int* doneF = (unsigned int*)(wsb + WS_DONE_OFF);
    unsigned int* refW  = (unsigned int*)(wsb + WS_REF_OFF);
    const int tid = threadIdx.x;

    const unsigned int P =
        __hip_atomic_load(refW, __ATOMIC_RELAXED, __HIP_MEMORY_SCOPE_AGENT);
    const unsigned int TOKEN = P ^ 0xA5A5A5A5u;

    __shared__ float2 sva[8][132];
    __shared__ float2 svb[8][132];

    // ================= Phase A: emb + V build (blocks 0..255) =================
    // Byte-identical math to the R8 emb_v_kernel (native trig, verified).
    if (blockIdx.x < NS) {
        const int s = blockIdx.x;
        const int t = tid;
        __shared__ float emb[EMB];
        __shared__ float ctA[NBLK], stA[NBLK], exA[NBLK], eyA[NBLK];

        if (t < EMB) {
            const float* xr = x + s * 64;
            const float* wr = W + t * 64;
            float acc = bias[t];
            #pragma unroll
            for (int k = 0; k < 64; ++k) acc = fmaf(xr[k], wr[k], acc);
            float e = 1.0f / (1.0f + __expf(-acc));
            emb[t] = e;
            out_emb[s * EMB + t] = e;
        }
        __syncthreads();

        if (t < NBLK) {
            float th = emb[2 * t]     * 1.57079632679489662f;  // pi/2
            float ph = emb[2 * t + 1] * 6.28318530717958648f;  // 2*pi
            float st = __sinf(th), ct = __cosf(th);
            float sp = __sinf(ph), cp = __cosf(ph);
            ctA[t] = ct; stA[t] = st; exA[t] = cp; eyA[t] = sp;
        }
        __syncthreads();

        if (t < NPH) {
            const int c = t;  // column 0..7
            float2 u[MODES];
            #pragma unroll
            for (int m = 0; m < MODES; ++m) {
                u[m].x = (m == c) ? 1.0f : 0.0f;
                u[m].y = 0.0f;
            }
            int bi = 0;
            #pragma unroll
            for (int d = 0; d < 8; ++d) {
                const int off = d & 1;
                const int nb = 8 - off;
                #pragma unroll
                for (int k = 0; k < nb; ++k) {
                    float ct = ctA[bi], st = stA[bi], ex = exA[bi], ey = eyA[bi];
                    ++bi;
                    const int r0 = off + 2 * k;
                    float2 u0 = u[r0], u1 = u[r0 + 1];
                    float2 n0, n1;
                    n0.x = ex * ct * u0.x - ey * ct * u0.y - st * u1.x;
                    n0.y = ex * ct * u0.y + ey * ct * u0.x - st * u1.y;
                    n1.x = ex * st * u0.x - ey * st * u0.y + ct * u1.x;
                    n1.y = ex * st * u0.y + ey * st * u0.x + ct * u1.y;
                    u[r0] = n0; u[r0 + 1] = n1;
                }
            }
            #pragma unroll
            for (int m = 0; m < MODES; ++m)
                Vws[(s * MODES + m) * NPH + c] = u[m];
        }
        __syncthreads();   // all Vws writes done before publishing
        if (t == 0) {
            // RELEASE at AGENT scope: flushes this XCD's prior writes (Vws,
            // out_emb) to the coherence point, then publishes the flag.
            __hip_atomic_store(&doneF[s * 16], TOKEN,
                               __ATOMIC_RELEASE, __HIP_MEMORY_SCOPE_AGENT);
        }
    }

    // ================= Phase B: permanent (all 528 blocks) =================
    // triangular decode: blockIdx -> (ta, tb), ta <= tb (R0 verbatim)
    const int L = blockIdx.x;
    int t = (int)((65.0f - sqrtf(4225.0f - 8.0f * (float)L)) * 0.5f);
    while (t * (65 - t) / 2 > L) --t;
    while ((t + 1) * (65 - (t + 1)) / 2 <= L) ++t;
    const int ta = t;
    const int tb = ta + (L - t * (65 - t) / 2);

    // wait for the 16 producer samples this tile pair needs
    if (tid < 16) {
        const int smp = (tid < 8) ? (ta * 8 + tid) : (tb * 8 + (tid - 8));
        // bounded spin (insurance only; co-residency guarantees progress)
        for (int it = 0; it < (1 << 24); ++it) {
            if (__hip_atomic_load(&doneF[smp * 16], __ATOMIC_ACQUIRE,
                                  __HIP_MEMORY_SCOPE_AGENT) == TOKEN) break;
            __builtin_amdgcn_s_sleep(2);
        }
    }
    __syncthreads();

    // stage Vws via AGENT-scope 64-bit atomic loads (bypass stale per-XCD L2)
    {
        const unsigned long long* srcA =
            (const unsigned long long*)(Vws + (size_t)ta * 8 * 128);
        const unsigned long long* srcB =
            (const unsigned long long*)(Vws + (size_t)tb * 8 * 128);
        #pragma unroll
        for (int r = 0; r < 4; ++r) {
            int idx = r * 256 + tid;       // 0..1023 float2s
            int row = idx >> 7;
            int c   = idx & 127;
            unsigned long long va = __hip_atomic_load(
                srcA + idx, __ATOMIC_RELAXED, __HIP_MEMORY_SCOPE_AGENT);
            unsigned long long vb = __hip_atomic_load(
                srcB + idx, __ATOMIC_RELAXED, __HIP_MEMORY_SCOPE_AGENT);
            sva[row][c] = __builtin_bit_cast(float2, va);
            svb[row][c] = __builtin_bit_cast(float2, vb);
        }
    }
    __syncthreads();

    const int p   = tid >> 2;    // pair 0..63 (quad-aligned lanes)
    const int sub = tid & 3;
    const int h   = sub & 1;     // row half
    const int e   = sub >> 1;    // delta7 half
    const int pa  = p >> 3;
    const int pb  = p & 7;

    // ---- build own 2 rows: rows 4h+2e, 4h+2e+1 of G = Va^H Vb ----
    v2f Go[2][8];
    #pragma unroll
    for (int i = 0; i < 2; ++i)
        #pragma unroll
        for (int j = 0; j < 8; ++j) Go[i][j] = (v2f){0.f, 0.f};

    #pragma unroll 2
    for (int m = 0; m < 16; ++m) {
        float4 va4 = *(const float4*)&sva[pa][m * 8 + 4 * h + 2 * e];
        v2f a0 = {va4.x, va4.y};
        v2f a1 = {va4.z, va4.w};
        v2f vb[8];
        #pragma unroll
        for (int jj = 0; jj < 4; ++jj) {
            float4 b4 = *(const float4*)&svb[pb][m * 8 + 2 * jj];
            vb[2 * jj]     = (v2f){b4.x, b4.y};
            vb[2 * jj + 1] = (v2f){b4.z, b4.w};
        }
        #pragma unroll
        for (int j = 0; j < 8; ++j) {
            Go[0][j] = cfma_conj(a0, vb[j], Go[0][j]);
            Go[1][j] = cfma_conj(a1, vb[j], Go[1][j]);
        }
    }

    // ---- exchange 2 rows with delta-partner (xor 2) via DPP ----
    v2f Gp[2][8];
    #pragma unroll
    for (int i = 0; i < 2; ++i)
        #pragma unroll
        for (int j = 0; j < 8; ++j) {
            Gp[i][j].x = dpp_xor2(Go[i][j].x);
            Gp[i][j].y = dpp_xor2(Go[i][j].y);
        }

    // ---- rs init: delta = (+1,...,+1, sgn_e) ----
    const float sgn = 1.0f - 2.0f * (float)e;
    const v2f sgnv = {sgn, sgn};
    v2f rs[4];
    #pragma unroll
    for (int r = 0; r < 2; ++r) {
        {
            v2f s = ((Go[r][0] + Go[r][1]) + (Go[r][2] + Go[r][3]))
                  + ((Go[r][4] + Go[r][5]) + Go[r][6]);
            rs[r] = sgnv * Go[r][7] + s;
        }
        {
            v2f s = ((Gp[r][0] + Gp[r][1]) + (Gp[r][2] + Gp[r][3]))
                  + ((Gp[r][4] + Gp[r][5]) + Gp[r][6]);
            rs[2 + r] = sgnv * Gp[r][7] + s;
        }
    }

    v2f acc;

#define TREE(OUT) do {                                                \
        v2f t01 = cmul(rs[0], rs[1]);                                 \
        v2f t23 = cmul(rs[2], rs[3]);                                 \
        v2f half_ = cmul(t01, t23);                                   \
        v2f oth;                                                      \
        oth.x = dpp_xor1(half_.x);                                    \
        oth.y = dpp_xor1(half_.y);                                    \
        OUT = cmul(half_, oth);                                       \
    } while (0)

#define UPD(J, S) do {                                                \
        const v2f sv = {(S), (S)};                                    \
        rs[0] = sv * Go[0][J] + rs[0];                                \
        rs[1] = sv * Go[1][J] + rs[1];                                \
        rs[2] = sv * Gp[0][J] + rs[2];                                \
        rs[3] = sv * Gp[1][J] + rs[3];                                \
    } while (0)

#define TERM(TS) do {                                                 \
        v2f fullp; TREE(fullp);                                       \
        const v2f tv = {(TS), (TS)};                                  \
        acc = tv * fullp + acc;                                       \
    } while (0)

    TREE(acc);                              // t=0, sign +
    UPD(1, -2.f); TERM(-1.f);               // t=1
    UPD(2, -2.f); TERM( 1.f);               // t=2
    UPD(1,  2.f); TERM(-1.f);               // t=3
    UPD(3, -2.f); TERM( 1.f);               // t=4
    UPD(1, -2.f); TERM(-1.f);               // t=5
    UPD(2,  2.f); TERM( 1.f);               // t=6
    UPD(1,  2.f); TERM(-1.f);               // t=7
    UPD(4, -2.f); TERM( 1.f);               // t=8
    UPD(1, -2.f); TERM(-1.f);               // t=9
    UPD(2, -2.f); TERM( 1.f);               // t=10
    UPD(1,  2.f); TERM(-1.f);               // t=11
    UPD(3,  2.f); TERM( 1.f);               // t=12
    UPD(1, -2.f); TERM(-1.f);               // t=13
    UPD(2,  2.f); TERM( 1.f);               // t=14
    UPD(1,  2.f); TERM(-1.f);               // t=15
    UPD(5, -2.f); TERM( 1.f);               // t=16
    UPD(1, -2.f); TERM(-1.f);               // t=17
    UPD(2, -2.f); TERM( 1.f);               // t=18
    UPD(1,  2.f); TERM(-1.f);               // t=19
    UPD(3, -2.f); TERM( 1.f);               // t=20
    UPD(1, -2.f); TERM(-1.f);               // t=21
    UPD(2,  2.f); TERM( 1.f);               // t=22
    UPD(1,  2.f); TERM(-1.f);               // t=23
    UPD(4,  2.f); TERM( 1.f);               // t=24
    UPD(1, -2.f); TERM(-1.f);               // t=25
    UPD(2, -2.f); TERM( 1.f);               // t=26
    UPD(1,  2.f); TERM(-1.f);               // t=27
    UPD(3,  2.f); TERM( 1.f);               // t=28
    UPD(1, -2.f); TERM(-1.f);               // t=29
    UPD(2,  2.f); TERM( 1.f);               // t=30
    UPD(1,  2.f); TERM(-1.f);               // t=31
    UPD(6, -2.f); TERM( 1.f);               // t=32
    UPD(1, -2.f); TERM(-1.f);               // t=33
    UPD(2, -2.f); TERM( 1.f);               // t=34
    UPD(1,  2.f); TERM(-1.f);               // t=35
    UPD(3, -2.f); TERM( 1.f);               // t=36
    UPD(1, -2.f); TERM(-1.f);               // t=37
    UPD(2,  2.f); TERM( 1.f);               // t=38
    UPD(1,  2.f); TERM(-1.f);               // t=39
    UPD(4, -2.f); TERM( 1.f);               // t=40
    UPD(1, -2.f); TERM(-1.f);               // t=41
    UPD(2, -2.f); TERM( 1.f);               // t=42
    UPD(1,  2.f); TERM(-1.f);               // t=43
    UPD(3,  2.f); TERM( 1.f);               // t=44
    UPD(1, -2.f); TERM(-1.f);               // t=45
    UPD(2,  2.f); TERM( 1.f);               // t=46
    UPD(1,  2.f); TERM(-1.f);               // t=47
    UPD(5,  2.f); TERM( 1.f);               // t=48
    UPD(1, -2.f); TERM(-1.f);               // t=49
    UPD(2, -2.f); TERM( 1.f);               // t=50
    UPD(1,  2.f); TERM(-1.f);               // t=51
    UPD(3, -2.f); TERM( 1.f);               // t=52
    UPD(1, -2.f); TERM(-1.f);               // t=53
    UPD(2,  2.f); TERM( 1.f);               // t=54
    UPD(1,  2.f); TERM(-1.f);               // t=55
    UPD(4,  2.f); TERM( 1.f);               // t=56
    UPD(1, -2.f); TERM(-1.f);               // t=57
    UPD(2, -2.f); TERM( 1.f);               // t=58
    UPD(1,  2.f); TERM(-1.f);               // t=59
    UPD(3,  2.f); TERM( 1.f);               // t=60
    UPD(1, -2.f); TERM(-1.f);               // t=61
    UPD(2,  2.f); TERM( 1.f);               // t=62
    UPD(1,  2.f); TERM(-1.f);               // t=63
#undef UPD
#undef TERM
#undef TREE

    // fold delta7 sign, then combine the two delta-halves (xor 2, DPP)
    float ax = sgn * acc.x, ay = sgn * acc.y;
    ax += dpp_xor2(ax);
    ay += dpp_xor2(ay);

    if (sub == 0) {
        const int a = ta * 8 + pa;
        const int b = tb * 8 + pb;
        float K = fmaf(ax, ax, ay * ay) * (1.0f / 16384.0f);
        if (a == b) K = 1.0f;
        outK[a * 256 + b] = K;
        outK[b * 256 + a] = K;   // Hermitian symmetry
    }
}

extern "C" void kernel_launch(void* const* d_in, const int* in_sizes, int n_in,
                              void* d_out, int out_size, void* d_ws, size_t ws_size,
                              hipStream_t stream) {
    const float* x    = (const float*)d_in[0];   // 256*64
    const float* W    = (const float*)d_in[1];   // 120*64
    const float* bias = (const float*)d_in[2];   // 120
    float* out     = (float*)d_out;
    float* out_emb = out;              // 256*120
    float* outK    = out + NS * EMB;   // 256*256
    float2* Vws    = (float2*)d_ws;    // 256 KB at ws base
    unsigned char* wsb = (unsigned char*)d_ws;
    (void)in_sizes; (void)n_in; (void)ws_size;

    fused_flag_kernel<<<528, 256, 0, stream>>>(x, W, bias, out_emb, outK, Vws, wsb);
}

// Round 10
// 82.976 us; speedup vs baseline: 1.3411x; 1.3411x over previous
//
#include <hip/hip_runtime.h>
#include <math.h>

#define NS 256
#define EMB 120
#define MODES 16
#define NPH 8

typedef float v2f __attribute__((ext_vector_type(2)));

// complex mul
__device__ __forceinline__ v2f cmul(v2f a, v2f b) {
    v2f axx = {a.x, a.x};
    v2f nyy = {-a.y, a.y};
    v2f byx = {b.y, b.x};
    return axx * b + nyy * byx;   // {ax*bx - ay*by, ax*by + ay*bx}
}
// r = conj(a)*b + c
__device__ __forceinline__ v2f cfma_conj(v2f a, v2f b, v2f c) {
    v2f axx = {a.x, a.x};
    v2f pyy = {a.y, -a.y};
    v2f byx = {b.y, b.x};
    return axx * b + (pyy * byx + c);
}

// Cross-lane xor within quad via DPP quad_perm (VALU, not LDS pipe).
// xor1: [1,0,3,2] -> ctrl 0xB1 ; xor2: [2,3,0,1] -> ctrl 0x4E
__device__ __forceinline__ float dpp_xor1(float x) {
    return __builtin_bit_cast(float,
        __builtin_amdgcn_mov_dpp(__builtin_bit_cast(int, x), 0xB1, 0xF, 0xF, true));
}
__device__ __forceinline__ float dpp_xor2(float x) {
    return __builtin_bit_cast(float,
        __builtin_amdgcn_mov_dpp(__builtin_bit_cast(int, x), 0x4E, 0xF, 0xF, true));
}

// Fused kernel v3 = R3 (verified, passed) with ONE change: all libm
// transcendental CALLS replaced by native HW instructions.
// Theory: R3's ~35us kernel = ~10us arithmetic + ~20us of 960 libm
// sincosf calls/block (pointer-return -> scratch round-trips + branchy
// OCML sequence, nothing to hide it at 2 blocks/CU). R8 proved native
// trig is bf16-identical in this problem (absmax unchanged). R9 proved
// cross-block sync is worse than redundant recompute. One node, zero
// sync hazards, prologue redundancy now ~free.
__global__ __launch_bounds__(256, 2) void fused_perm_kernel(
    const float* __restrict__ x, const float* __restrict__ W,
    const float* __restrict__ bias, float* __restrict__ out_emb,
    float* __restrict__ outK)
{
    __shared__ __align__(16) float2 sva[8][132];
    __shared__ __align__(16) float2 svb[8][132];
    __shared__ __align__(16) float  xls[16][64];       // staged x rows
    __shared__ float  embl[16][120];                   // sigmoid outputs
    __shared__ __align__(16) float  angl[16][61][4];   // ct,st,ex,ey per (slot, block)
    __shared__ __align__(16) float  wld[120][68];      // W rows, pitch-68 (bank spread)

    // triangular decode: blockIdx -> (ta, tb), ta <= tb  (32 tiles of 8 samples)
    const int L = blockIdx.x;
    int t = (int)((65.0f - sqrtf(4225.0f - 8.0f * (float)L)) * 0.5f);
    while (t * (65 - t) / 2 > L) --t;
    while ((t + 1) * (65 - (t + 1)) / 2 <= L) ++t;
    const int ta = t;
    const int tb = ta + (L - t * (65 - t) / 2);

    const int tid = threadIdx.x;

    // ---- P1a: stage the 16 slots' x rows (slot 0..7 = tile a, 8..15 = tile b) ----
    {
        const int i  = tid >> 4;          // slot
        const int q  = tid & 15;          // float4 within row
        const int si = (i < 8) ? (ta * 8 + i) : (tb * 8 + (i - 8));
        const float4 xv = ((const float4*)(x + (size_t)si * 64))[q];
        *(float4*)&xls[i][q * 4] = xv;
    }
    // ---- P1b: stage W coalesced into LDS (1920 float4) ----
    {
        const float4* Wg = (const float4*)W;
        #pragma unroll
        for (int r = 0; r < 8; ++r) {
            const int idx = r * 256 + tid;          // 0..2047
            if (idx < 1920) {
                const int j = idx >> 4;
                const int q = idx & 15;
                const float4 w = Wg[idx];
                *(float4*)&wld[j][q * 4] = w;
            }
        }
    }
    __syncthreads();

    // ---- P2: emb = sigmoid(x @ W.T + b), register-blocked ----
    // lane owns output column j (W row cached in 64 VGPRs, read once from LDS);
    // loops over 8 sample slots with broadcast x reads.
    // fmaf chain order identical to the original kernel.
    {
        const int j  = tid & 127;
        const int ig = tid >> 7;          // slot group: 0 -> slots 0..7, 1 -> 8..15
        if (j < EMB) {
            float4 wr[16];
            #pragma unroll
            for (int k4 = 0; k4 < 16; ++k4)
                wr[k4] = *(const float4*)&wld[j][k4 * 4];
            const float bj = bias[j];
            #pragma unroll
            for (int ii = 0; ii < 8; ++ii) {
                const int i = ig * 8 + ii;
                float acc = bj;
                #pragma unroll
                for (int k4 = 0; k4 < 16; ++k4) {
                    const float4 xv = *(const float4*)&xls[i][k4 * 4];
                    acc = fmaf(xv.x, wr[k4].x, acc);
                    acc = fmaf(xv.y, wr[k4].y, acc);
                    acc = fmaf(xv.z, wr[k4].z, acc);
                    acc = fmaf(xv.w, wr[k4].w, acc);
                }
                const float e = 1.0f / (1.0f + __expf(-acc));   // native v_exp_f32
                embl[i][j] = e;
                if (ta == tb && i < 8)
                    out_emb[(size_t)(ta * 8 + i) * EMB + j] = e;
            }
        }
    }
    __syncthreads();

    // ---- P3: angles: 16 slots x 60 blocks = 960 tasks over 256 threads ----
    // native v_sin/v_cos (args tiny: theta in (0,pi/2), phi in (0,2pi));
    // no OCML call, no pointer-return scratch traffic.
    #pragma unroll
    for (int r = 0; r < 4; ++r) {
        const int idx = tid + 256 * r;
        if (idx < 960) {
            const int i = idx / 60;
            const int b = idx - i * 60;
            const float th = embl[i][2 * b]     * 1.57079632679489662f;  // pi/2
            const float ph = embl[i][2 * b + 1] * 6.28318530717958648f;  // 2*pi
            const float st = __sinf(th), ct = __cosf(th);
            const float sp = __sinf(ph), cp = __cosf(ph);
            angl[i][b][0] = ct; angl[i][b][1] = st;
            angl[i][b][2] = cp; angl[i][b][3] = sp;
        }
    }
    __syncthreads();

    // ---- P4: build V columns: 16 slots x 8 cols = 128 builder threads ----
    if (tid < 128) {
        const int i = tid >> 3;
        const int c = tid & 7;
        float2 u[MODES];
        #pragma unroll
        for (int m = 0; m < MODES; ++m) {
            u[m].x = (m == c) ? 1.0f : 0.0f;
            u[m].y = 0.0f;
        }
        int bi = 0;
        #pragma unroll
        for (int d = 0; d < 8; ++d) {
            const int off = d & 1;
            const int nb = 8 - off;
            #pragma unroll
            for (int k = 0; k < nb; ++k) {
                const float4 a4 = *(const float4*)&angl[i][bi][0];
                const float ct = a4.x, st = a4.y, ex = a4.z, ey = a4.w;
                ++bi;
                const int r0 = off + 2 * k;
                float2 u0 = u[r0], u1 = u[r0 + 1];
                float2 n0, n1;
                n0.x = ex * ct * u0.x - ey * ct * u0.y - st * u1.x;
                n0.y = ex * ct * u0.y + ey * ct * u0.x - st * u1.y;
                n1.x = ex * st * u0.x - ey * st * u0.y + ct * u1.x;
                n1.y = ex * st * u0.y + ey * st * u0.x + ct * u1.y;
                u[r0] = n0; u[r0 + 1] = n1;
            }
        }
        float2* dst = (i < 8) ? &sva[i][0] : &svb[i - 8][0];
        #pragma unroll
        for (int m = 0; m < MODES; ++m)
            dst[m * 8 + c] = u[m];   // layout: [row][m*8 + col], matches G-build reads
    }
    __syncthreads();

    // ---- permanent core: verified round-0 version (64 terms, 4 lanes/pair) ----
    const int p   = tid >> 2;    // pair 0..63 (quad-aligned lanes)
    const int sub = tid & 3;
    const int h   = sub & 1;     // row half
    const int e   = sub >> 1;    // delta7 half
    const int pa  = p >> 3;
    const int pb  = p & 7;

    v2f Go[2][8];
    #pragma unroll
    for (int i = 0; i < 2; ++i)
        #pragma unroll
        for (int j = 0; j < 8; ++j) Go[i][j] = (v2f){0.f, 0.f};

    #pragma unroll 2
    for (int m = 0; m < 16; ++m) {
        float4 va4 = *(const float4*)&sva[pa][m * 8 + 4 * h + 2 * e];
        v2f a0 = {va4.x, va4.y};
        v2f a1 = {va4.z, va4.w};
        v2f vb[8];
        #pragma unroll
        for (int jj = 0; jj < 4; ++jj) {
            float4 b4 = *(const float4*)&svb[pb][m * 8 + 2 * jj];
            vb[2 * jj]     = (v2f){b4.x, b4.y};
            vb[2 * jj + 1] = (v2f){b4.z, b4.w};
        }
        #pragma unroll
        for (int j = 0; j < 8; ++j) {
            Go[0][j] = cfma_conj(a0, vb[j], Go[0][j]);
            Go[1][j] = cfma_conj(a1, vb[j], Go[1][j]);
        }
    }

    v2f Gp[2][8];
    #pragma unroll
    for (int i = 0; i < 2; ++i)
        #pragma unroll
        for (int j = 0; j < 8; ++j) {
            Gp[i][j].x = dpp_xor2(Go[i][j].x);
            Gp[i][j].y = dpp_xor2(Go[i][j].y);
        }

    const float sgn = 1.0f - 2.0f * (float)e;
    const v2f sgnv = {sgn, sgn};
    v2f rs[4];
    #pragma unroll
    for (int r = 0; r < 2; ++r) {
        {
            v2f s = ((Go[r][0] + Go[r][1]) + (Go[r][2] + Go[r][3]))
                  + ((Go[r][4] + Go[r][5]) + Go[r][6]);
            rs[r] = sgnv * Go[r][7] + s;
        }
        {
            v2f s = ((Gp[r][0] + Gp[r][1]) + (Gp[r][2] + Gp[r][3]))
                  + ((Gp[r][4] + Gp[r][5]) + Gp[r][6]);
            rs[2 + r] = sgnv * Gp[r][7] + s;
        }
    }

    v2f acc;

#define TREE(OUT) do {                                                \
        v2f t01 = cmul(rs[0], rs[1]);                                 \
        v2f t23 = cmul(rs[2], rs[3]);                                 \
        v2f half_ = cmul(t01, t23);                                   \
        v2f oth;                                                      \
        oth.x = dpp_xor1(half_.x);                                    \
        oth.y = dpp_xor1(half_.y);                                    \
        OUT = cmul(half_, oth);                                       \
    } while (0)

#define UPD(J, S) do {                                                \
        const v2f sv = {(S), (S)};                                    \
        rs[0] = sv * Go[0][J] + rs[0];                                \
        rs[1] = sv * Go[1][J] + rs[1];                                \
        rs[2] = sv * Gp[0][J] + rs[2];                                \
        rs[3] = sv * Gp[1][J] + rs[3];                                \
    } while (0)

#define TERM(TS) do {                                                 \
        v2f fullp; TREE(fullp);                                       \
        const v2f tv = {(TS), (TS)};                                  \
        acc = tv * fullp + acc;                                       \
    } while (0)

    TREE(acc);                              // t=0, sign +
    UPD(1, -2.f); TERM(-1.f);               // t=1
    UPD(2, -2.f); TERM( 1.f);               // t=2
    UPD(1,  2.f); TERM(-1.f);               // t=3
    UPD(3, -2.f); TERM( 1.f);               // t=4
    UPD(1, -2.f); TERM(-1.f);               // t=5
    UPD(2,  2.f); TERM( 1.f);               // t=6
    UPD(1,  2.f); TERM(-1.f);               // t=7
    UPD(4, -2.f); TERM( 1.f);               // t=8
    UPD(1, -2.f); TERM(-1.f);               // t=9
    UPD(2, -2.f); TERM( 1.f);               // t=10
    UPD(1,  2.f); TERM(-1.f);               // t=11
    UPD(3,  2.f); TERM( 1.f);               // t=12
    UPD(1, -2.f); TERM(-1.f);               // t=13
    UPD(2,  2.f); TERM( 1.f);               // t=14
    UPD(1,  2.f); TERM(-1.f);               // t=15
    UPD(5, -2.f); TERM( 1.f);               // t=16
    UPD(1, -2.f); TERM(-1.f);               // t=17
    UPD(2, -2.f); TERM( 1.f);               // t=18
    UPD(1,  2.f); TERM(-1.f);               // t=19
    UPD(3, -2.f); TERM( 1.f);               // t=20
    UPD(1, -2.f); TERM(-1.f);               // t=21
    UPD(2,  2.f); TERM( 1.f);               // t=22
    UPD(1,  2.f); TERM(-1.f);               // t=23
    UPD(4,  2.f); TERM( 1.f);               // t=24
    UPD(1, -2.f); TERM(-1.f);               // t=25
    UPD(2, -2.f); TERM( 1.f);               // t=26
    UPD(1,  2.f); TERM(-1.f);               // t=27
    UPD(3,  2.f); TERM( 1.f);               // t=28
    UPD(1, -2.f); TERM(-1.f);               // t=29
    UPD(2,  2.f); TERM( 1.f);               // t=30
    UPD(1,  2.f); TERM(-1.f);               // t=31
    UPD(6, -2.f); TERM( 1.f);               // t=32
    UPD(1, -2.f); TERM(-1.f);               // t=33
    UPD(2, -2.f); TERM( 1.f);               // t=34
    UPD(1,  2.f); TERM(-1.f);               // t=35
    UPD(3, -2.f); TERM( 1.f);               // t=36
    UPD(1, -2.f); TERM(-1.f);               // t=37
    UPD(2,  2.f); TERM( 1.f);               // t=38
    UPD(1,  2.f); TERM(-1.f);               // t=39
    UPD(4, -2.f); TERM( 1.f);               // t=40
    UPD(1, -2.f); TERM(-1.f);               // t=41
    UPD(2, -2.f); TERM( 1.f);               // t=42
    UPD(1,  2.f); TERM(-1.f);               // t=43
    UPD(3,  2.f); TERM( 1.f);               // t=44
    UPD(1, -2.f); TERM(-1.f);               // t=45
    UPD(2,  2.f); TERM( 1.f);               // t=46
    UPD(1,  2.f); TERM(-1.f);               // t=47
    UPD(5,  2.f); TERM( 1.f);               // t=48
    UPD(1, -2.f); TERM(-1.f);               // t=49
    UPD(2, -2.f); TERM( 1.f);               // t=50
    UPD(1,  2.f); TERM(-1.f);               // t=51
    UPD(3, -2.f); TERM( 1.f);               // t=52
    UPD(1, -2.f); TERM(-1.f);               // t=53
    UPD(2,  2.f); TERM( 1.f);               // t=54
    UPD(1,  2.f); TERM(-1.f);               // t=55
    UPD(4,  2.f); TERM( 1.f);               // t=56
    UPD(1, -2.f); TERM(-1.f);               // t=57
    UPD(2, -2.f); TERM( 1.f);               // t=58
    UPD(1,  2.f); TERM(-1.f);               // t=59
    UPD(3,  2.f); TERM( 1.f);               // t=60
    UPD(1, -2.f); TERM(-1.f);               // t=61
    UPD(2,  2.f); TERM( 1.f);               // t=62
    UPD(1,  2.f); TERM(-1.f);               // t=63
#undef UPD
#undef TERM
#undef TREE

    // fold delta7 sign, then combine the two delta-halves (xor 2, DPP)
    float ax = sgn * acc.x, ay = sgn * acc.y;
    ax += dpp_xor2(ax);
    ay += dpp_xor2(ay);

    if (sub == 0) {
        const int a = ta * 8 + pa;
        const int b = tb * 8 + pb;
        float K = fmaf(ax, ax, ay * ay) * (1.0f / 16384.0f);
        if (a == b) K = 1.0f;
        outK[a * 256 + b] = K;
        outK[b * 256 + a] = K;   // Hermitian symmetry
    }
}

extern "C" void kernel_launch(void* const* d_in, const int* in_sizes, int n_in,
                              void* d_out, int out_size, void* d_ws, size_t ws_size,
                              hipStream_t stream) {
    const float* x    = (const float*)d_in[0];   // 256*64
    const float* W    = (const float*)d_in[1];   // 120*64
    const float* bias = (const float*)d_in[2];   // 120
    float* out     = (float*)d_out;
    float* out_emb = out;              // 256*120
    float* outK    = out + NS * EMB;   // 256*256
    (void)d_ws; (void)ws_size; (void)in_sizes; (void)n_in;

    fused_perm_kernel<<<528, 256, 0, stream>>>(x, W, bias, out_emb, outK);
}

// Round 11
// 74.527 us; speedup vs baseline: 1.4931x; 1.1134x over previous
//
#include <hip/hip_runtime.h>
#include <math.h>

#define NS 256
#define EMB 120
#define NBLK 60
#define MODES 16
#define NPH 8

typedef float v2f __attribute__((ext_vector_type(2)));

// complex mul
__device__ __forceinline__ v2f cmul(v2f a, v2f b) {
    v2f axx = {a.x, a.x};
    v2f nyy = {-a.y, a.y};
    v2f byx = {b.y, b.x};
    return axx * b + nyy * byx;   // {ax*bx - ay*by, ax*by + ay*bx}
}
// r = conj(a)*b + c
__device__ __forceinline__ v2f cfma_conj(v2f a, v2f b, v2f c) {
    v2f axx = {a.x, a.x};
    v2f pyy = {a.y, -a.y};
    v2f byx = {b.y, b.x};
    return axx * b + (pyy * byx + c);
}

// Cross-lane xor within quad via DPP quad_perm (VALU, not LDS pipe).
// xor1: [1,0,3,2] -> ctrl 0xB1 ; xor2: [2,3,0,1] -> ctrl 0x4E
__device__ __forceinline__ float dpp_xor1(float x) {
    return __builtin_bit_cast(float,
        __builtin_amdgcn_mov_dpp(__builtin_bit_cast(int, x), 0xB1, 0xF, 0xF, true));
}
__device__ __forceinline__ float dpp_xor2(float x) {
    return __builtin_bit_cast(float,
        __builtin_amdgcn_mov_dpp(__builtin_bit_cast(int, x), 0x4E, 0xF, 0xF, true));
}
// xor4 crosses quads: ds_swizzle butterfly, offset = (xor_mask<<10)|0x1F
__device__ __forceinline__ float swz_xor4(float x) {
    return __builtin_bit_cast(float,
        __builtin_amdgcn_ds_swizzle(__builtin_bit_cast(int, x), 0x101F));
}

// FINAL (R8 verbatim — session best, 74.77us, absmax 9.54e-7).
// Kernel A: R0 structure with native transcendentals (v_exp/v_sin/v_cos;
// args tiny, precision ~1e-5 << 2e-2 bf16 threshold).
__global__ __launch_bounds__(128) void emb_v_kernel(
    const float* __restrict__ x, const float* __restrict__ W,
    const float* __restrict__ bias, float* __restrict__ out_emb,
    float2* __restrict__ Vws)
{
    const int s = blockIdx.x;
    const int t = threadIdx.x;
    __shared__ float emb[EMB];
    __shared__ float ctA[NBLK], stA[NBLK], exA[NBLK], eyA[NBLK];

    if (t < EMB) {
        const float* xr = x + s * 64;
        const float* wr = W + t * 64;
        float acc = bias[t];
        #pragma unroll
        for (int k = 0; k < 64; ++k) acc = fmaf(xr[k], wr[k], acc);
        float e = 1.0f / (1.0f + __expf(-acc));   // native v_exp_f32 path
        emb[t] = e;
        out_emb[s * EMB + t] = e;
    }
    __syncthreads();

    if (t < NBLK) {
        float th = emb[2 * t]     * 1.57079632679489662f;  // pi/2
        float ph = emb[2 * t + 1] * 6.28318530717958648f;  // 2*pi
        float st = __sinf(th), ct = __cosf(th);            // native v_sin/v_cos
        float sp = __sinf(ph), cp = __cosf(ph);
        ctA[t] = ct; stA[t] = st; exA[t] = cp; eyA[t] = sp;
    }
    __syncthreads();

    if (t < NPH) {
        const int c = t;  // column 0..7
        float2 u[MODES];
        #pragma unroll
        for (int m = 0; m < MODES; ++m) {
            u[m].x = (m == c) ? 1.0f : 0.0f;
            u[m].y = 0.0f;
        }
        int bi = 0;
        #pragma unroll
        for (int d = 0; d < 8; ++d) {
            const int off = d & 1;
            const int nb = 8 - off;
            #pragma unroll
            for (int k = 0; k < nb; ++k) {
                float ct = ctA[bi], st = stA[bi], ex = exA[bi], ey = eyA[bi];
                ++bi;
                const int r0 = off + 2 * k;
                float2 u0 = u[r0], u1 = u[r0 + 1];
                float2 n0, n1;
                n0.x = ex * ct * u0.x - ey * ct * u0.y - st * u1.x;
                n0.y = ex * ct * u0.y + ey * ct * u0.x - st * u1.y;
                n1.x = ex * st * u0.x - ey * st * u0.y + ct * u1.x;
                n1.y = ex * st * u0.y + ey * st * u0.x + ct * u1.y;
                u[r0] = n0; u[r0 + 1] = n1;
            }
        }
        #pragma unroll
        for (int m = 0; m < MODES; ++m)
            Vws[(s * MODES + m) * NPH + c] = u[m];
    }
}

// Kernel B: R6 perm (verified) — 8 lanes/pair, dedup'd G-build (f splits
// m-halves, combined via ds_swizzle xor4), 32-term Gray ladder, 1056 blocks
// at 4 blocks/CU.
__global__ __launch_bounds__(256, 4) void perm_kernel(
    const float2* __restrict__ Vws, float* __restrict__ outK)
{
    __shared__ float2 sva[8][132];
    __shared__ float2 svb[8][132];

    // triangular decode: blockIdx>>1 -> (ta, tb), ta <= tb; blockIdx&1 -> pa half
    const int L  = blockIdx.x >> 1;
    const int hb = blockIdx.x & 1;
    int t = (int)((65.0f - sqrtf(4225.0f - 8.0f * (float)L)) * 0.5f);
    while (t * (65 - t) / 2 > L) --t;
    while ((t + 1) * (65 - (t + 1)) / 2 <= L) ++t;
    const int ta = t;
    const int tb = ta + (L - t * (65 - t) / 2);

    const int tid = threadIdx.x;
    const float4* srcA = (const float4*)(Vws + (size_t)ta * 8 * 128);
    const float4* srcB = (const float4*)(Vws + (size_t)tb * 8 * 128);
    #pragma unroll
    for (int r = 0; r < 2; ++r) {
        int idx = r * 256 + tid;       // 0..511
        int row = idx >> 6;
        int c4  = idx & 63;
        *(float4*)&sva[row][c4 * 2] = srcA[idx];
        *(float4*)&svb[row][c4 * 2] = srcB[idx];
    }
    __syncthreads();

    const int p   = tid >> 3;        // pair 0..31 (8-lane aligned groups)
    const int sub = tid & 7;
    const int h   = sub & 1;         // row half       (dpp xor1 partner)
    const int e   = (sub >> 1) & 1;  // delta7 half    (dpp xor2 partner)
    const int f   = sub >> 2;        // m-half + delta6 half (swizzle xor4 partner)
    const int pa  = (hb << 2) | (p >> 3);   // 0..7
    const int pb  = p & 7;

    // ---- build own 2 rows of G = Va^H Vb, m-half only (split by f) ----
    v2f Go[2][8];
    #pragma unroll
    for (int i = 0; i < 2; ++i)
        #pragma unroll
        for (int j = 0; j < 8; ++j) Go[i][j] = (v2f){0.f, 0.f};

    const int mbase = f * 8;
    #pragma unroll
    for (int m = 0; m < 8; ++m) {
        const int mm = mbase + m;
        float4 va4 = *(const float4*)&sva[pa][mm * 8 + 4 * h + 2 * e];
        v2f a0 = {va4.x, va4.y};
        v2f a1 = {va4.z, va4.w};
        v2f vb[8];
        #pragma unroll
        for (int jj = 0; jj < 4; ++jj) {
            float4 b4 = *(const float4*)&svb[pb][mm * 8 + 2 * jj];
            vb[2 * jj]     = (v2f){b4.x, b4.y};
            vb[2 * jj + 1] = (v2f){b4.z, b4.w};
        }
        #pragma unroll
        for (int j = 0; j < 8; ++j) {
            Go[0][j] = cfma_conj(a0, vb[j], Go[0][j]);
            Go[1][j] = cfma_conj(a1, vb[j], Go[1][j]);
        }
    }

    // ---- combine the two m-halves across the f bit (xor 4, LDS swizzle) ----
    #pragma unroll
    for (int i = 0; i < 2; ++i)
        #pragma unroll
        for (int j = 0; j < 8; ++j) {
            Go[i][j].x += swz_xor4(Go[i][j].x);
            Go[i][j].y += swz_xor4(Go[i][j].y);
        }

    // ---- exchange 2 rows with e-partner (xor 2) via DPP ----
    v2f Gp[2][8];
    #pragma unroll
    for (int i = 0; i < 2; ++i)
        #pragma unroll
        for (int j = 0; j < 8; ++j) {
            Gp[i][j].x = dpp_xor2(Go[i][j].x);
            Gp[i][j].y = dpp_xor2(Go[i][j].y);
        }

    // ---- rs init: delta = (+1,...,+1, sgn_f @ col6, sgn_e @ col7) ----
    const float sgne = 1.0f - 2.0f * (float)e;
    const float sgnf = 1.0f - 2.0f * (float)f;
    const v2f sev = {sgne, sgne};
    const v2f sfv = {sgnf, sgnf};
    v2f rs[4];
    #pragma unroll
    for (int r = 0; r < 2; ++r) {
        {
            v2f s = ((Go[r][0] + Go[r][1]) + (Go[r][2] + Go[r][3]))
                  + (Go[r][4] + Go[r][5]);
            s = sfv * Go[r][6] + s;
            rs[r] = sev * Go[r][7] + s;
        }
        {
            v2f s = ((Gp[r][0] + Gp[r][1]) + (Gp[r][2] + Gp[r][3]))
                  + (Gp[r][4] + Gp[r][5]);
            s = sfv * Gp[r][6] + s;
            rs[2 + r] = sev * Gp[r][7] + s;
        }
    }

    v2f acc;

#define TREE(OUT) do {                                                \
        v2f t01 = cmul(rs[0], rs[1]);                                 \
        v2f t23 = cmul(rs[2], rs[3]);                                 \
        v2f half_ = cmul(t01, t23);                                   \
        v2f oth;                                                      \
        oth.x = dpp_xor1(half_.x);                                    \
        oth.y = dpp_xor1(half_.y);                                    \
        OUT = cmul(half_, oth);                                       \
    } while (0)

#define UPD(J, S) do {                                                \
        const v2f sv = {(S), (S)};                                    \
        rs[0] = sv * Go[0][J] + rs[0];                                \
        rs[1] = sv * Go[1][J] + rs[1];                                \
        rs[2] = sv * Gp[0][J] + rs[2];                                \
        rs[3] = sv * Gp[1][J] + rs[3];                                \
    } while (0)

#define TERM(TS) do {                                                 \
        v2f fullp; TREE(fullp);                                       \
        const v2f tv = {(TS), (TS)};                                  \
        acc = tv * fullp + acc;                                       \
    } while (0)

    // 32-term Gray ladder over delta1..delta5 (verified in rounds 2/6)
    TREE(acc);                              // t=0, sign +
    UPD(1, -2.f); TERM(-1.f);               // t=1
    UPD(2, -2.f); TERM( 1.f);               // t=2
    UPD(1,  2.f); TERM(-1.f);               // t=3
    UPD(3, -2.f); TERM( 1.f);               // t=4
    UPD(1, -2.f); TERM(-1.f);               // t=5
    UPD(2,  2.f); TERM( 1.f);               // t=6
    UPD(1,  2.f); TERM(-1.f);               // t=7
    UPD(4, -2.f); TERM( 1.f);               // t=8
    UPD(1, -2.f); TERM(-1.f);               // t=9
    UPD(2, -2.f); TERM( 1.f);               // t=10
    UPD(1,  2.f); TERM(-1.f);               // t=11
    UPD(3,  2.f); TERM( 1.f);               // t=12
    UPD(1, -2.f); TERM(-1.f);               // t=13
    UPD(2,  2.f); TERM( 1.f);               // t=14
    UPD(1,  2.f); TERM(-1.f);               // t=15
    UPD(5, -2.f); TERM( 1.f);               // t=16
    UPD(1, -2.f); TERM(-1.f);               // t=17
    UPD(2, -2.f); TERM( 1.f);               // t=18
    UPD(1,  2.f); TERM(-1.f);               // t=19
    UPD(3, -2.f); TERM( 1.f);               // t=20
    UPD(1, -2.f); TERM(-1.f);               // t=21
    UPD(2,  2.f); TERM( 1.f);               // t=22
    UPD(1,  2.f); TERM(-1.f);               // t=23
    UPD(4,  2.f); TERM( 1.f);               // t=24
    UPD(1, -2.f); TERM(-1.f);               // t=25
    UPD(2, -2.f); TERM( 1.f);               // t=26
    UPD(1,  2.f); TERM(-1.f);               // t=27
    UPD(3,  2.f); TERM( 1.f);               // t=28
    UPD(1, -2.f); TERM(-1.f);               // t=29
    UPD(2,  2.f); TERM( 1.f);               // t=30
    UPD(1,  2.f); TERM(-1.f);               // t=31
#undef UPD
#undef TERM
#undef TREE

    // fold delta6*delta7 coefficient, then sum the four (e,f) lane variants:
    // e via DPP xor2, f via ds_swizzle xor4.
    const float cf = sgne * sgnf;
    float ax = cf * acc.x, ay = cf * acc.y;
    ax += dpp_xor2(ax);
    ay += dpp_xor2(ay);
    ax += swz_xor4(ax);
    ay += swz_xor4(ay);

    if (sub == 0) {
        const int a = ta * 8 + pa;
        const int b = tb * 8 + pb;
        float K = fmaf(ax, ax, ay * ay) * (1.0f / 16384.0f);
        if (a == b) K = 1.0f;
        outK[a * 256 + b] = K;
        outK[b * 256 + a] = K;   // Hermitian symmetry
    }
}

extern "C" void kernel_launch(void* const* d_in, const int* in_sizes, int n_in,
                              void* d_out, int out_size, void* d_ws, size_t ws_size,
                              hipStream_t stream) {
    const float* x    = (const float*)d_in[0];   // 256*64
    const float* W    = (const float*)d_in[1];   // 120*64
    const float* bias = (const float*)d_in[2];   // 120
    float* out     = (float*)d_out;
    float* out_emb = out;              // 256*120
    float* outK    = out + NS * EMB;   // 256*256
    float2* Vws    = (float2*)d_ws;    // 256*16*8 float2 = 256 KB

    emb_v_kernel<<<NS, 128, 0, stream>>>(x, W, bias, out_emb, Vws);
    perm_kernel<<<1056, 256, 0, stream>>>(Vws, outK);
}